// Round 3
// baseline (241.986 us; speedup 1.0000x reference)
//
#include <hip/hip_runtime.h>
#include <hip/hip_bf16.h>

typedef __hip_bfloat16 bf16;
typedef unsigned short ushort;
typedef unsigned int uint;
typedef __attribute__((ext_vector_type(8))) short short8;
typedef __attribute__((ext_vector_type(4))) float f32x4;

#define Bn 8
#define Cn 256
#define Nn 4096          // H*W
#define Mn 1024          // pooled
#define EPSf 1e-5f

__device__ __forceinline__ float b2f(const bf16 v){ return __bfloat162float(v); }
__device__ __forceinline__ ushort f2bu(float f){
  uint u = __float_as_uint(f);
  return (ushort)((u + 0x7FFFu + ((u >> 16) & 1u)) >> 16);
}

// ---------------- transpose: x[b][c][p] fp32 -> xT[b][p][c] bf16
__global__ __launch_bounds__(256) void transpose_kernel(
    const float* __restrict__ x, bf16* __restrict__ xT)
{
  __shared__ float xs[64][65];
  const int t = threadIdx.x;
  const int p0 = blockIdx.x*64, c0 = blockIdx.y*64, b = blockIdx.z;
  #pragma unroll
  for (int i = 0; i < 16; ++i) {
    int idx = t + i*256; int cl = idx >> 6, pl = idx & 63;
    xs[cl][pl] = x[((long)(b*Cn) + c0 + cl)*Nn + p0 + pl];
  }
  __syncthreads();
  ushort* xTu = (ushort*)xT;
  #pragma unroll
  for (int i = 0; i < 8; ++i) {
    int idx = t + i*256; int pl = idx >> 5, cp = idx & 31;
    uint u = (uint)f2bu(xs[cp*2][pl]) | ((uint)f2bu(xs[cp*2+1][pl]) << 16);
    *(uint*)(xTu + ((long)(b*Nn) + p0 + pl)*Cn + c0 + cp*2) = u;
  }
}

// ---------------- build combined weights Wcomb[384][256] bf16 + bcomb[384] fp32
__global__ __launch_bounds__(256) void wcomb_kernel(
    const float* __restrict__ tw, const float* __restrict__ tb,
    const float* __restrict__ pw, const float* __restrict__ pb,
    const float* __restrict__ gw, const float* __restrict__ gb,
    bf16* __restrict__ Wcomb, float* __restrict__ bcomb)
{
  const int r = blockIdx.x, c = threadIdx.x;
  float v;
  if (r < 64)        v = (c < 64)  ? tw[r*64 + c]            : 0.f;
  else if (r < 128)  v = (c >= 64) ? pw[(r-64)*192 + (c-64)] : 0.f;
  else               v = gw[(r-128)*256 + c];
  Wcomb[r*256 + c] = __float2bfloat16(v);
  if (c == 0)
    bcomb[r] = (r < 64) ? tb[r] : (r < 128) ? pb[r-64] : gb[r-128];
}

// ---------------- fused front GEMM + pooling: emits Q, K, Vt directly
// grid (32 px (h-pairs), 3 o-tiles, 8 b), block 256 (4 waves, 2x2 of 64x64)
__global__ __launch_bounds__(256) void gemm384_kernel(
    const bf16* __restrict__ xT, const bf16* __restrict__ Wcomb,
    const float* __restrict__ bcomb, bf16* __restrict__ Q,
    bf16* __restrict__ K, bf16* __restrict__ Vt)
{
  __shared__ union {
    struct { ushort As[128*40]; ushort Bs[128*40]; } g;
    float Pb[2][128][33];
  } sm;
  const int t = threadIdx.x;
  const int px = blockIdx.x, o0 = blockIdx.y*128, b = blockIdx.z;
  const int p0 = px*128;
  const int lane = t & 63, w = t >> 6;
  const int ql = lane & 15, quad = lane >> 4;
  const int wm = (w & 1)*64, wn = (w >> 1)*64;
  const ushort* xTu = (const ushort*)xT;
  const ushort* Wu  = (const ushort*)Wcomb;

  f32x4 acc[4][4];
  #pragma unroll
  for (int i = 0; i < 4; ++i)
    #pragma unroll
    for (int j = 0; j < 4; ++j) acc[i][j] = (f32x4){0.f,0.f,0.f,0.f};

  for (int kc = 0; kc < 8; ++kc) {
    __syncthreads();
    #pragma unroll
    for (int i = 0; i < 2; ++i) {
      int idx = t + i*256; int r = idx >> 2, cq = idx & 3;
      *(uint4*)(sm.g.As + r*40 + cq*8) =
          *(const uint4*)(xTu + ((long)(b*Nn) + p0 + r)*Cn + kc*32 + cq*8);
      *(uint4*)(sm.g.Bs + r*40 + cq*8) =
          *(const uint4*)(Wu + (o0 + r)*Cn + kc*32 + cq*8);
    }
    __syncthreads();
    short8 aF[4], bF[4];
    #pragma unroll
    for (int mi = 0; mi < 4; ++mi)
      aF[mi] = *(const short8*)(sm.g.As + (wm + mi*16 + ql)*40 + quad*8);
    #pragma unroll
    for (int ni = 0; ni < 4; ++ni)
      bF[ni] = *(const short8*)(sm.g.Bs + (wn + ni*16 + ql)*40 + quad*8);
    #pragma unroll
    for (int mi = 0; mi < 4; ++mi)
      #pragma unroll
      for (int ni = 0; ni < 4; ++ni)
        acc[mi][ni] = __builtin_amdgcn_mfma_f32_16x16x32_bf16(aF[mi], bF[ni], acc[mi][ni], 0, 0, 0);
  }
  float bias[4];
  #pragma unroll
  for (int ni = 0; ni < 4; ++ni) bias[ni] = bcomb[o0 + wn + ni*16 + ql];

  if (o0 == 0 && wn == 0) {
    #pragma unroll
    for (int mi = 0; mi < 4; ++mi)
      #pragma unroll
      for (int ni = 0; ni < 4; ++ni)
        #pragma unroll
        for (int r = 0; r < 4; ++r) {
          int p = p0 + wm + mi*16 + quad*4 + r;
          Q[((long)(b*Nn) + p)*64 + ni*16 + ql] = __float2bfloat16(acc[mi][ni][r] + bias[ni]);
        }
  }
  __syncthreads();
  if (o0 != 0 || wn == 64) {
    int g = w & 1;
    #pragma unroll
    for (int mi = 0; mi < 4; ++mi)
      #pragma unroll
      for (int ni = 0; ni < 4; ++ni) {
        float a0 = acc[mi][ni][0] + bias[ni], a1 = acc[mi][ni][1] + bias[ni];
        float a2 = acc[mi][ni][2] + bias[ni], a3 = acc[mi][ni][3] + bias[ni];
        int o = wn + ni*16 + ql;
        int wp = mi*8 + quad*2;
        sm.Pb[g][o][wp]     = fmaxf(a0, a1);
        sm.Pb[g][o][wp + 1] = fmaxf(a2, a3);
      }
  }
  __syncthreads();
  if (o0 == 0) {
    int wp = t & 31, og = t >> 5;
    ushort kv[8];
    #pragma unroll
    for (int j = 0; j < 8; ++j) {
      int o = 64 + og*8 + j;
      kv[j] = f2bu(fmaxf(sm.Pb[0][o][wp], sm.Pb[1][o][wp]));
    }
    *(uint4*)((ushort*)K + ((long)(b*Mn) + px*32 + wp)*64 + og*8) = *(uint4*)kv;
  } else {
    int ol = t >> 1, wp0 = (t & 1)*16;
    ushort vv[16];
    #pragma unroll
    for (int j = 0; j < 16; ++j)
      vv[j] = f2bu(fmaxf(sm.Pb[0][ol][wp0 + j], sm.Pb[1][ol][wp0 + j]));
    ushort* dst = (ushort*)Vt + ((long)(b*Cn) + (o0 - 128) + ol)*Mn + px*32 + wp0;
    *(uint4*)dst       = *(uint4*)(vv);
    *(uint4*)(dst + 8) = *(uint4*)(vv + 8);
  }
}

// ---------------- MFMA flash attention v7: LDS bypass for K and V.
// K ([M][64]) and Vt ([C][M]) layouts let the MFMA B-fragments be loaded
// DIRECTLY from L2 into operand registers (short8 at row*ld + quad*8):
// staging them through LDS was a pure global->reg->LDS->reg round trip
// (V has zero intra-block reuse; K only 4x on an 8KB tile, L2-resident).
// v7 keeps only P in LDS (layout genuinely changes between QK-output and
// PV-input wave partitions), double-buffered -> ONE barrier per iteration
// (was 3). K/V fragments are register-prefetched one tile ahead.
//   QK: wave w -> q-row tile rt=w&3 (16 rows), key half kh=w>>2 (32 keys)
//   PV: wave w -> row half rh=(w&1)*32, col quarter cq=(w>>1)*64
__global__ __launch_bounds__(512) void attn_kernel(
    const bf16* __restrict__ Q, const bf16* __restrict__ K, const bf16* __restrict__ Vt,
    bf16* __restrict__ Y)
{
  __shared__ __align__(16) ushort Ps[2][64*68];
  __shared__ float l_sh[2][64];

  const int t = threadIdx.x;
  const int b = blockIdx.y, q0 = blockIdx.x*64;
  const int lane = t & 63, w = t >> 6;        // 8 waves
  const int ql = lane & 15, quad = lane >> 4;
  const int rt = w & 3;                        // QK row tile (16 rows)
  const int kh = w >> 2;                       // QK key half (32 keys)
  const int rh = (w & 1)*32;                   // PV local row base
  const int cq = (w >> 1)*64;                  // PV col base (64 cols)
  const ushort* Qu = (const ushort*)Q;
  const ushort* Ku = (const ushort*)K;
  const ushort* Vu = (const ushort*)Vt;

  const long qrow = (long)(b*Nn) + q0 + rt*16 + ql;
  short8 aQ0 = *(const short8*)(Qu + qrow*64 + quad*8);
  short8 aQ1 = *(const short8*)(Qu + qrow*64 + 32 + quad*8);

  // direct-fragment base pointers
  // K fragment (ct, half): kbase + (m0 + ct*16)*64 + half*32
  const ushort* kbase = Ku + ((long)(b*Mn) + kh*32 + ql)*64 + quad*8;
  // V fragment (ci, half): vbase + ci*16*Mn + m0 + half*32
  const ushort* vbase = Vu + ((long)(b*Cn) + cq + ql)*Mn + quad*8;

  float lrow[4];
  #pragma unroll
  for (int r = 0; r < 4; ++r) lrow[r] = 0.f;

  f32x4 acc[2][4];
  #pragma unroll
  for (int mi = 0; mi < 2; ++mi)
    #pragma unroll
    for (int ci = 0; ci < 4; ++ci) acc[mi][ci] = (f32x4){0.f,0.f,0.f,0.f};

  // prologue: fragments for tile 0
  short8 kf[4], vf[8];
  #pragma unroll
  for (int ct = 0; ct < 2; ++ct) {
    kf[ct*2]   = *(const short8*)(kbase + ct*16*64);
    kf[ct*2+1] = *(const short8*)(kbase + ct*16*64 + 32);
  }
  #pragma unroll
  for (int ci = 0; ci < 4; ++ci) {
    vf[ci*2]   = *(const short8*)(vbase + ci*16*Mn);
    vf[ci*2+1] = *(const short8*)(vbase + ci*16*Mn + 32);
  }

  int buf = 0;
  for (int mt = 0; mt < 16; ++mt) {
    const int m1 = ((mt + 1) & 15)*64;   // clamped wrap: tile-0 reload on last iter (discarded)
    // ---- QK^T from registers: this wave's 16 q-rows x its 32-key half
    #pragma unroll
    for (int ct = 0; ct < 2; ++ct) {
      int kb = kh*32 + ct*16;
      f32x4 s = (f32x4){0.f,0.f,0.f,0.f};
      s = __builtin_amdgcn_mfma_f32_16x16x32_bf16(aQ0, kf[ct*2],   s, 0, 0, 0);
      s = __builtin_amdgcn_mfma_f32_16x16x32_bf16(aQ1, kf[ct*2+1], s, 0, 0, 0);
      #pragma unroll
      for (int r = 0; r < 4; ++r) {
        float e = __expf(s[r]);
        lrow[r] += e;
        Ps[buf][(rt*16 + quad*4 + r)*68 + kb + ql] = f2bu(e);
      }
    }
    // prefetch next tile's K fragments (kf consumed above)
    #pragma unroll
    for (int ct = 0; ct < 2; ++ct) {
      kf[ct*2]   = *(const short8*)(kbase + (m1 + ct*16)*64);
      kf[ct*2+1] = *(const short8*)(kbase + (m1 + ct*16)*64 + 32);
    }
    __syncthreads();   // publish Ps[buf]
    // ---- PV from registers: P(32 rows) x V(64 keys x this wave's 64 cols)
    short8 aP0[2], aP1[2];
    #pragma unroll
    for (int mi = 0; mi < 2; ++mi) {
      aP0[mi] = *(const short8*)(&Ps[buf][(rh + mi*16 + ql)*68 + quad*8]);
      aP1[mi] = *(const short8*)(&Ps[buf][(rh + mi*16 + ql)*68 + 32 + quad*8]);
    }
    #pragma unroll
    for (int ci = 0; ci < 4; ++ci) {
      #pragma unroll
      for (int mi = 0; mi < 2; ++mi) {
        acc[mi][ci] = __builtin_amdgcn_mfma_f32_16x16x32_bf16(aP0[mi], vf[ci*2],   acc[mi][ci], 0, 0, 0);
        acc[mi][ci] = __builtin_amdgcn_mfma_f32_16x16x32_bf16(aP1[mi], vf[ci*2+1], acc[mi][ci], 0, 0, 0);
      }
    }
    // prefetch next tile's V fragments (vf consumed above; in flight across
    // the next QK + barrier, used at next PV)
    #pragma unroll
    for (int ci = 0; ci < 4; ++ci) {
      vf[ci*2]   = *(const short8*)(vbase + ci*16*Mn + m1);
      vf[ci*2+1] = *(const short8*)(vbase + ci*16*Mn + m1 + 32);
    }
    buf ^= 1;
  }
  // reduce l across the 16 ql lanes; each (rt,kh) wave owns a partial sum
  #pragma unroll
  for (int r = 0; r < 4; ++r)
    #pragma unroll
    for (int off = 1; off < 16; off <<= 1)
      lrow[r] += __shfl_xor(lrow[r], off, 64);
  if (ql == 0) {
    #pragma unroll
    for (int r = 0; r < 4; ++r) l_sh[kh][rt*16 + quad*4 + r] = lrow[r];
  }
  __syncthreads();
  #pragma unroll
  for (int mi = 0; mi < 2; ++mi)
    #pragma unroll
    for (int r = 0; r < 4; ++r) {
      int row = rh + mi*16 + quad*4 + r;
      float inv = 1.f / (l_sh[0][row] + l_sh[1][row]);
      #pragma unroll
      for (int ci = 0; ci < 4; ++ci)
        Y[((long)(b*Nn) + q0 + row)*256 + cq + ci*16 + ql] = __float2bfloat16(acc[mi][ci][r]*inv);
    }
}

// ---------------- wconv MFMA GEMM: out[b][o][n] = Ww @ Y^T, BN, +x
__global__ __launch_bounds__(256) void wconv_kernel(
    const bf16* __restrict__ Y, const float* __restrict__ Ww, const float* __restrict__ Wb,
    const float* __restrict__ gamma, const float* __restrict__ beta,
    const float* __restrict__ mean, const float* __restrict__ var,
    const float* __restrict__ x, float* __restrict__ out)
{
  __shared__ __align__(16) ushort As[128*40];
  __shared__ __align__(16) ushort Bs[128*40];
  __shared__ float ssc[128], ssh[128];
  const int t = threadIdx.x;
  const int n0 = blockIdx.x*128, o0 = blockIdx.y*128, b = blockIdx.z;
  const int lane = t & 63, w = t >> 6;
  const int ql = lane & 15, quad = lane >> 4;
  const int wm = (w & 1)*64, wn = (w >> 1)*64;
  const ushort* Yu = (const ushort*)Y;

  if (t < 128) {
    int o = o0 + t;
    float sc = gamma[o] * rsqrtf(var[o] + EPSf);
    ssc[t] = sc;
    ssh[t] = (Wb[o] - mean[o])*sc + beta[o];
  }

  f32x4 acc[4][4];
  #pragma unroll
  for (int i = 0; i < 4; ++i)
    #pragma unroll
    for (int j = 0; j < 4; ++j) acc[i][j] = (f32x4){0.f,0.f,0.f,0.f};

  for (int kc = 0; kc < 8; ++kc) {
    __syncthreads();
    #pragma unroll
    for (int i = 0; i < 4; ++i) {
      int idx = t + i*256; int r = idx >> 3, cq = idx & 7;
      float4 v = *(const float4*)(Ww + (o0 + r)*Cn + kc*32 + cq*4);
      uint lo = (uint)f2bu(v.x) | ((uint)f2bu(v.y) << 16);
      uint hi = (uint)f2bu(v.z) | ((uint)f2bu(v.w) << 16);
      *(uint2*)(As + r*40 + cq*4) = make_uint2(lo, hi);
    }
    #pragma unroll
    for (int i = 0; i < 2; ++i) {
      int idx = t + i*256; int r = idx >> 2, cq = idx & 3;
      *(uint4*)(Bs + r*40 + cq*8) =
          *(const uint4*)(Yu + ((long)(b*Nn) + n0 + r)*Cn + kc*32 + cq*8);
    }
    __syncthreads();
    short8 aF[4], bF[4];
    #pragma unroll
    for (int mi = 0; mi < 4; ++mi)
      aF[mi] = *(const short8*)(As + (wm + mi*16 + ql)*40 + quad*8);
    #pragma unroll
    for (int ni = 0; ni < 4; ++ni)
      bF[ni] = *(const short8*)(Bs + (wn + ni*16 + ql)*40 + quad*8);
    #pragma unroll
    for (int mi = 0; mi < 4; ++mi)
      #pragma unroll
      for (int ni = 0; ni < 4; ++ni)
        acc[mi][ni] = __builtin_amdgcn_mfma_f32_16x16x32_bf16(aF[mi], bF[ni], acc[mi][ni], 0, 0, 0);
  }
  #pragma unroll
  for (int mi = 0; mi < 4; ++mi)
    #pragma unroll
    for (int r = 0; r < 4; ++r) {
      int ol = wm + mi*16 + quad*4 + r;
      int o = o0 + ol;
      float sc = ssc[ol], sh = ssh[ol];
      #pragma unroll
      for (int ni = 0; ni < 4; ++ni) {
        int n = n0 + wn + ni*16 + ql;
        long gidx = ((long)(b*Cn + o))*Nn + n;
        out[gidx] = acc[mi][ni][r]*sc + sh + x[gidx];
      }
    }
}

extern "C" void kernel_launch(void* const* d_in, const int* in_sizes, int n_in,
                              void* d_out, int out_size, void* d_ws, size_t ws_size,
                              hipStream_t stream)
{
  const float* x       = (const float*)d_in[0];
  const float* g_w     = (const float*)d_in[1];
  const float* g_b     = (const float*)d_in[2];
  const float* theta_w = (const float*)d_in[3];
  const float* theta_b = (const float*)d_in[4];
  const float* phi_w   = (const float*)d_in[5];
  const float* phi_b   = (const float*)d_in[6];
  const float* W_w     = (const float*)d_in[7];
  const float* W_b     = (const float*)d_in[8];
  const float* bn_g    = (const float*)d_in[9];
  const float* bn_b    = (const float*)d_in[10];
  const float* bn_m    = (const float*)d_in[11];
  const float* bn_v    = (const float*)d_in[12];
  float* out = (float*)d_out;

  bf16* wsb = (bf16*)d_ws;
  bf16* xT    = wsb;                  // B*N*C = 8,388,608 (dead after gemm384)
  bf16* Y     = wsb;                  // alias xT
  bf16* Q     = wsb + 8388608;        // B*N*64  = 2,097,152
  bf16* K     = wsb + 10485760;       // B*M*64  =   524,288
  bf16* Vt    = wsb + 11010048;       // B*C*M   = 2,097,152
  bf16* Wcomb = wsb + 13107200;       // 384*256 =    98,304
  float* bcomb = (float*)(wsb + 13205504);  // 384 fp32

  transpose_kernel<<<dim3(64, 4, Bn), 256, 0, stream>>>(x, xT);
  wcomb_kernel<<<dim3(384), 256, 0, stream>>>(theta_w, theta_b, phi_w, phi_b, g_w, g_b, Wcomb, bcomb);
  gemm384_kernel<<<dim3(32, 3, Bn), 256, 0, stream>>>(xT, Wcomb, bcomb, Q, K, Vt);
  attn_kernel<<<dim3(64, Bn), 512, 0, stream>>>(Q, K, Vt, Y);
  wconv_kernel<<<dim3(32, 2, Bn), 256, 0, stream>>>(Y, W_w, W_b, bn_g, bn_b, bn_m, bn_v, x, out);
}

// Round 4
// 182.693 us; speedup vs baseline: 1.3245x; 1.3245x over previous
//
#include <hip/hip_runtime.h>
#include <hip/hip_bf16.h>

typedef __hip_bfloat16 bf16;
typedef unsigned short ushort;
typedef unsigned int uint;
typedef __attribute__((ext_vector_type(8))) short short8;
typedef __attribute__((ext_vector_type(4))) float f32x4;

#define Bn 8
#define Cn 256
#define Nn 4096          // H*W
#define Mn 1024          // pooled
#define EPSf 1e-5f

__device__ __forceinline__ float b2f(const bf16 v){ return __bfloat162float(v); }
__device__ __forceinline__ ushort f2bu(float f){
  uint u = __float_as_uint(f);
  return (ushort)((u + 0x7FFFu + ((u >> 16) & 1u)) >> 16);
}

// ---------------- transpose: x[b][c][p] fp32 -> xT[b][p][c] bf16
__global__ __launch_bounds__(256) void transpose_kernel(
    const float* __restrict__ x, bf16* __restrict__ xT)
{
  __shared__ float xs[64][65];
  const int t = threadIdx.x;
  const int p0 = blockIdx.x*64, c0 = blockIdx.y*64, b = blockIdx.z;
  #pragma unroll
  for (int i = 0; i < 16; ++i) {
    int idx = t + i*256; int cl = idx >> 6, pl = idx & 63;
    xs[cl][pl] = x[((long)(b*Cn) + c0 + cl)*Nn + p0 + pl];
  }
  __syncthreads();
  ushort* xTu = (ushort*)xT;
  #pragma unroll
  for (int i = 0; i < 8; ++i) {
    int idx = t + i*256; int pl = idx >> 5, cp = idx & 31;
    uint u = (uint)f2bu(xs[cp*2][pl]) | ((uint)f2bu(xs[cp*2+1][pl]) << 16);
    *(uint*)(xTu + ((long)(b*Nn) + p0 + pl)*Cn + c0 + cp*2) = u;
  }
}

// ---------------- build combined weights Wcomb[384][256] bf16 + bcomb[384] fp32
__global__ __launch_bounds__(256) void wcomb_kernel(
    const float* __restrict__ tw, const float* __restrict__ tb,
    const float* __restrict__ pw, const float* __restrict__ pb,
    const float* __restrict__ gw, const float* __restrict__ gb,
    bf16* __restrict__ Wcomb, float* __restrict__ bcomb)
{
  const int r = blockIdx.x, c = threadIdx.x;
  float v;
  if (r < 64)        v = (c < 64)  ? tw[r*64 + c]            : 0.f;
  else if (r < 128)  v = (c >= 64) ? pw[(r-64)*192 + (c-64)] : 0.f;
  else               v = gw[(r-128)*256 + c];
  Wcomb[r*256 + c] = __float2bfloat16(v);
  if (c == 0)
    bcomb[r] = (r < 64) ? tb[r] : (r < 128) ? pb[r-64] : gb[r-128];
}

// ---------------- fused front GEMM + pooling: emits Q, K, Vt directly
// grid (32 px (h-pairs), 3 o-tiles, 8 b), block 256 (4 waves, 2x2 of 64x64)
// v8: k-chunk reg-prefetch (same T14 pattern proven on attn v6): next chunk's
// global loads issued right after this chunk's LDS image is published.
__global__ __launch_bounds__(256) void gemm384_kernel(
    const bf16* __restrict__ xT, const bf16* __restrict__ Wcomb,
    const float* __restrict__ bcomb, bf16* __restrict__ Q,
    bf16* __restrict__ K, bf16* __restrict__ Vt)
{
  __shared__ union {
    struct { ushort As[128*40]; ushort Bs[128*40]; } g;
    float Pb[2][128][33];
  } sm;
  const int t = threadIdx.x;
  const int px = blockIdx.x, o0 = blockIdx.y*128, b = blockIdx.z;
  const int p0 = px*128;
  const int lane = t & 63, w = t >> 6;
  const int ql = lane & 15, quad = lane >> 4;
  const int wm = (w & 1)*64, wn = (w >> 1)*64;
  const ushort* xTu = (const ushort*)xT;
  const ushort* Wu  = (const ushort*)Wcomb;

  // staging geometry (fixed per thread)
  const int r0 = t >> 2, cq0 = t & 3;
  const int r1 = (t + 256) >> 2, cq1 = (t + 256) & 3;
  const ushort* aSrc0 = xTu + ((long)(b*Nn) + p0 + r0)*Cn + cq0*8;
  const ushort* aSrc1 = xTu + ((long)(b*Nn) + p0 + r1)*Cn + cq1*8;
  const ushort* bSrc0 = Wu + (o0 + r0)*Cn + cq0*8;
  const ushort* bSrc1 = Wu + (o0 + r1)*Cn + cq1*8;

  f32x4 acc[4][4];
  #pragma unroll
  for (int i = 0; i < 4; ++i)
    #pragma unroll
    for (int j = 0; j < 4; ++j) acc[i][j] = (f32x4){0.f,0.f,0.f,0.f};

  // prologue: chunk-0 loads into registers
  uint4 aReg0 = *(const uint4*)(aSrc0);
  uint4 aReg1 = *(const uint4*)(aSrc1);
  uint4 bReg0 = *(const uint4*)(bSrc0);
  uint4 bReg1 = *(const uint4*)(bSrc1);

  for (int kc = 0; kc < 8; ++kc) {
    __syncthreads();
    *(uint4*)(sm.g.As + r0*40 + cq0*8) = aReg0;
    *(uint4*)(sm.g.As + r1*40 + cq1*8) = aReg1;
    *(uint4*)(sm.g.Bs + r0*40 + cq0*8) = bReg0;
    *(uint4*)(sm.g.Bs + r1*40 + cq1*8) = bReg1;
    __syncthreads();
    if (kc < 7) {
      const int k1 = (kc + 1)*32;
      aReg0 = *(const uint4*)(aSrc0 + k1);
      aReg1 = *(const uint4*)(aSrc1 + k1);
      bReg0 = *(const uint4*)(bSrc0 + k1);
      bReg1 = *(const uint4*)(bSrc1 + k1);
    }
    short8 aF[4], bF[4];
    #pragma unroll
    for (int mi = 0; mi < 4; ++mi)
      aF[mi] = *(const short8*)(sm.g.As + (wm + mi*16 + ql)*40 + quad*8);
    #pragma unroll
    for (int ni = 0; ni < 4; ++ni)
      bF[ni] = *(const short8*)(sm.g.Bs + (wn + ni*16 + ql)*40 + quad*8);
    #pragma unroll
    for (int mi = 0; mi < 4; ++mi)
      #pragma unroll
      for (int ni = 0; ni < 4; ++ni)
        acc[mi][ni] = __builtin_amdgcn_mfma_f32_16x16x32_bf16(aF[mi], bF[ni], acc[mi][ni], 0, 0, 0);
  }
  float bias[4];
  #pragma unroll
  for (int ni = 0; ni < 4; ++ni) bias[ni] = bcomb[o0 + wn + ni*16 + ql];

  if (o0 == 0 && wn == 0) {
    #pragma unroll
    for (int mi = 0; mi < 4; ++mi)
      #pragma unroll
      for (int ni = 0; ni < 4; ++ni)
        #pragma unroll
        for (int r = 0; r < 4; ++r) {
          int p = p0 + wm + mi*16 + quad*4 + r;
          Q[((long)(b*Nn) + p)*64 + ni*16 + ql] = __float2bfloat16(acc[mi][ni][r] + bias[ni]);
        }
  }
  __syncthreads();
  if (o0 != 0 || wn == 64) {
    int g = w & 1;
    #pragma unroll
    for (int mi = 0; mi < 4; ++mi)
      #pragma unroll
      for (int ni = 0; ni < 4; ++ni) {
        float a0 = acc[mi][ni][0] + bias[ni], a1 = acc[mi][ni][1] + bias[ni];
        float a2 = acc[mi][ni][2] + bias[ni], a3 = acc[mi][ni][3] + bias[ni];
        int o = wn + ni*16 + ql;
        int wp = mi*8 + quad*2;
        sm.Pb[g][o][wp]     = fmaxf(a0, a1);
        sm.Pb[g][o][wp + 1] = fmaxf(a2, a3);
      }
  }
  __syncthreads();
  if (o0 == 0) {
    int wp = t & 31, og = t >> 5;
    ushort kv[8];
    #pragma unroll
    for (int j = 0; j < 8; ++j) {
      int o = 64 + og*8 + j;
      kv[j] = f2bu(fmaxf(sm.Pb[0][o][wp], sm.Pb[1][o][wp]));
    }
    *(uint4*)((ushort*)K + ((long)(b*Mn) + px*32 + wp)*64 + og*8) = *(uint4*)kv;
  } else {
    int ol = t >> 1, wp0 = (t & 1)*16;
    ushort vv[16];
    #pragma unroll
    for (int j = 0; j < 16; ++j)
      vv[j] = f2bu(fmaxf(sm.Pb[0][ol][wp0 + j], sm.Pb[1][ol][wp0 + j]));
    ushort* dst = (ushort*)Vt + ((long)(b*Cn) + (o0 - 128) + ol)*Mn + px*32 + wp0;
    *(uint4*)dst       = *(uint4*)(vv);
    *(uint4*)(dst + 8) = *(uint4*)(vv + 8);
  }
}

// ---------------- MFMA flash attention v6 (restored): reg-staged K/V prefetch.
// v7's LDS bypass regressed 2.3x (scattered 64B fragment loads, 2-4x per-wave
// redundancy, vmem latency on the MFMA critical path) -> staging through LDS
// with coalesced loads + one-tile reg prefetch is the right structure.
//   QK: wave w -> q-row tile rt=w&3 (16 rows), key half kh=w>>2 (32 keys)
//   PV: wave w -> row half rh=(w&1)*32, col quarter cq=(w>>1)*64
__global__ __launch_bounds__(512) void attn_kernel(
    const bf16* __restrict__ Q, const bf16* __restrict__ K, const bf16* __restrict__ Vt,
    bf16* __restrict__ Y)
{
  __shared__ __align__(16) ushort Ks[64*68];
  __shared__ __align__(16) ushort Vs[256*68];
  __shared__ __align__(16) ushort Ps[64*68];
  __shared__ float l_sh[2][64];

  const int t = threadIdx.x;
  const int b = blockIdx.y, q0 = blockIdx.x*64;
  const int lane = t & 63, w = t >> 6;        // 8 waves
  const int ql = lane & 15, quad = lane >> 4;
  const int rt = w & 3;                        // QK row tile (16 rows)
  const int kh = w >> 2;                       // QK key half (32 keys)
  const int rh = (w & 1)*32;                   // PV local row base
  const int cq = (w >> 1)*64;                  // PV col base (64 cols)
  const ushort* Qu = (const ushort*)Q;
  const ushort* Ku = (const ushort*)K;
  const ushort* Vu = (const ushort*)Vt;

  const long qrow = (long)(b*Nn) + q0 + rt*16 + ql;
  short8 aQ0 = *(const short8*)(Qu + qrow*64 + quad*8);
  short8 aQ1 = *(const short8*)(Qu + qrow*64 + 32 + quad*8);

  // staging geometry: thread -> (ch, rr); K row rr, V rows rr+64p
  const int ch = t & 7, rr = t >> 3;
  const ushort* kptr = Ku + ((long)(b*Mn) + rr)*64 + ch*8;       // + m0*64 per tile
  const ushort* vptr0 = Vu + ((long)(b*Cn) + rr      )*Mn + ch*8; // + m0 per tile
  const ushort* vptr1 = Vu + ((long)(b*Cn) + rr +  64)*Mn + ch*8;
  const ushort* vptr2 = Vu + ((long)(b*Cn) + rr + 128)*Mn + ch*8;
  const ushort* vptr3 = Vu + ((long)(b*Cn) + rr + 192)*Mn + ch*8;

  float lrow[4];
  #pragma unroll
  for (int r = 0; r < 4; ++r) lrow[r] = 0.f;

  f32x4 acc[2][4];
  #pragma unroll
  for (int mi = 0; mi < 2; ++mi)
    #pragma unroll
    for (int ci = 0; ci < 4; ++ci) acc[mi][ci] = (f32x4){0.f,0.f,0.f,0.f};

  // prologue: issue tile-0 K/V loads into registers
  uint4 kreg = *(const uint4*)(kptr);
  uint4 vreg0 = *(const uint4*)(vptr0);
  uint4 vreg1 = *(const uint4*)(vptr1);
  uint4 vreg2 = *(const uint4*)(vptr2);
  uint4 vreg3 = *(const uint4*)(vptr3);

  for (int mt = 0; mt < 16; ++mt) {
    __syncthreads();   // prev PV done reading Vs/Ps; prev QK done reading Ks
    // publish prefetched tile (compiler inserts vmcnt wait here; loads have
    // been in flight for a full compute phase)
    *(uint4*)(Ks + rr*68 + ch*8) = kreg;
    *(uint4*)(Vs + (rr      )*68 + ch*8) = vreg0;
    *(uint4*)(Vs + (rr +  64)*68 + ch*8) = vreg1;
    *(uint4*)(Vs + (rr + 128)*68 + ch*8) = vreg2;
    *(uint4*)(Vs + (rr + 192)*68 + ch*8) = vreg3;
    __syncthreads();
    // issue next tile's loads (hidden under QK + PV)
    if (mt < 15) {
      const int m1 = (mt + 1)*64;
      kreg  = *(const uint4*)(kptr + (long)m1*64);
      vreg0 = *(const uint4*)(vptr0 + m1);
      vreg1 = *(const uint4*)(vptr1 + m1);
      vreg2 = *(const uint4*)(vptr2 + m1);
      vreg3 = *(const uint4*)(vptr3 + m1);
    }
    // QK^T from LDS: this wave's 16 q-rows x its 32-key half
    #pragma unroll
    for (int ct = 0; ct < 2; ++ct) {
      int kb = kh*32 + ct*16;
      short8 b0 = *(const short8*)(Ks + (kb + ql)*68 + quad*8);
      short8 b1 = *(const short8*)(Ks + (kb + ql)*68 + 32 + quad*8);
      f32x4 s = (f32x4){0.f,0.f,0.f,0.f};
      s = __builtin_amdgcn_mfma_f32_16x16x32_bf16(aQ0, b0, s, 0, 0, 0);
      s = __builtin_amdgcn_mfma_f32_16x16x32_bf16(aQ1, b1, s, 0, 0, 0);
      #pragma unroll
      for (int r = 0; r < 4; ++r) {
        float e = __expf(s[r]);
        lrow[r] += e;
        Ps[(rt*16 + quad*4 + r)*68 + kb + ql] = f2bu(e);
      }
    }
    __syncthreads();
    // PV: P(32 rows) x V(64 keys x 64 cols)
    short8 aP0[2], aP1[2];
    #pragma unroll
    for (int mi = 0; mi < 2; ++mi) {
      aP0[mi] = *(const short8*)(Ps + (rh + mi*16 + ql)*68 + quad*8);
      aP1[mi] = *(const short8*)(Ps + (rh + mi*16 + ql)*68 + 32 + quad*8);
    }
    #pragma unroll
    for (int ci = 0; ci < 4; ++ci) {
      short8 b0 = *(const short8*)(Vs + (cq + ci*16 + ql)*68 + quad*8);
      short8 b1 = *(const short8*)(Vs + (cq + ci*16 + ql)*68 + 32 + quad*8);
      #pragma unroll
      for (int mi = 0; mi < 2; ++mi) {
        acc[mi][ci] = __builtin_amdgcn_mfma_f32_16x16x32_bf16(aP0[mi], b0, acc[mi][ci], 0, 0, 0);
        acc[mi][ci] = __builtin_amdgcn_mfma_f32_16x16x32_bf16(aP1[mi], b1, acc[mi][ci], 0, 0, 0);
      }
    }
  }
  // reduce l across the 16 ql lanes; each (rt,kh) wave owns a partial sum
  #pragma unroll
  for (int r = 0; r < 4; ++r)
    #pragma unroll
    for (int off = 1; off < 16; off <<= 1)
      lrow[r] += __shfl_xor(lrow[r], off, 64);
  if (ql == 0) {
    #pragma unroll
    for (int r = 0; r < 4; ++r) l_sh[kh][rt*16 + quad*4 + r] = lrow[r];
  }
  __syncthreads();
  #pragma unroll
  for (int mi = 0; mi < 2; ++mi)
    #pragma unroll
    for (int r = 0; r < 4; ++r) {
      int row = rh + mi*16 + quad*4 + r;
      float inv = 1.f / (l_sh[0][row] + l_sh[1][row]);
      #pragma unroll
      for (int ci = 0; ci < 4; ++ci)
        Y[((long)(b*Nn) + q0 + row)*256 + cq + ci*16 + ql] = __float2bfloat16(acc[mi][ci][r]*inv);
    }
}

// ---------------- wconv MFMA GEMM: out[b][o][n] = Ww @ Y^T, BN, +x
// v8: k-chunk reg-prefetch, same pattern as gemm384.
__global__ __launch_bounds__(256) void wconv_kernel(
    const bf16* __restrict__ Y, const float* __restrict__ Ww, const float* __restrict__ Wb,
    const float* __restrict__ gamma, const float* __restrict__ beta,
    const float* __restrict__ mean, const float* __restrict__ var,
    const float* __restrict__ x, float* __restrict__ out)
{
  __shared__ __align__(16) ushort As[128*40];
  __shared__ __align__(16) ushort Bs[128*40];
  __shared__ float ssc[128], ssh[128];
  const int t = threadIdx.x;
  const int n0 = blockIdx.x*128, o0 = blockIdx.y*128, b = blockIdx.z;
  const int lane = t & 63, w = t >> 6;
  const int ql = lane & 15, quad = lane >> 4;
  const int wm = (w & 1)*64, wn = (w >> 1)*64;
  const ushort* Yu = (const ushort*)Y;

  if (t < 128) {
    int o = o0 + t;
    float sc = gamma[o] * rsqrtf(var[o] + EPSf);
    ssc[t] = sc;
    ssh[t] = (Wb[o] - mean[o])*sc + beta[o];
  }

  // staging geometry (fixed per thread)
  // A (weights, fp32->bf16): 4 slots of 8B; B (Y bf16): 2 slots of 16B
  const int ar[4] = { t >> 3, (t+256) >> 3, (t+512) >> 3, (t+768) >> 3 };
  const int ac[4] = { t & 7,  (t+256) & 7,  (t+512) & 7,  (t+768) & 7 };
  const int br0 = t >> 2, bc0 = t & 3;
  const int br1 = (t+256) >> 2, bc1 = (t+256) & 3;
  const float* aSrc[4] = {
    Ww + (o0 + ar[0])*Cn + ac[0]*4, Ww + (o0 + ar[1])*Cn + ac[1]*4,
    Ww + (o0 + ar[2])*Cn + ac[2]*4, Ww + (o0 + ar[3])*Cn + ac[3]*4 };
  const ushort* bSrc0 = Yu + ((long)(b*Nn) + n0 + br0)*Cn + bc0*8;
  const ushort* bSrc1 = Yu + ((long)(b*Nn) + n0 + br1)*Cn + bc1*8;

  f32x4 acc[4][4];
  #pragma unroll
  for (int i = 0; i < 4; ++i)
    #pragma unroll
    for (int j = 0; j < 4; ++j) acc[i][j] = (f32x4){0.f,0.f,0.f,0.f};

  // prologue: chunk-0 loads
  float4 aReg[4];
  #pragma unroll
  for (int i = 0; i < 4; ++i) aReg[i] = *(const float4*)(aSrc[i]);
  uint4 bReg0 = *(const uint4*)(bSrc0);
  uint4 bReg1 = *(const uint4*)(bSrc1);

  for (int kc = 0; kc < 8; ++kc) {
    __syncthreads();
    #pragma unroll
    for (int i = 0; i < 4; ++i) {
      uint lo = (uint)f2bu(aReg[i].x) | ((uint)f2bu(aReg[i].y) << 16);
      uint hi = (uint)f2bu(aReg[i].z) | ((uint)f2bu(aReg[i].w) << 16);
      *(uint2*)(As + ar[i]*40 + ac[i]*4) = make_uint2(lo, hi);
    }
    *(uint4*)(Bs + br0*40 + bc0*8) = bReg0;
    *(uint4*)(Bs + br1*40 + bc1*8) = bReg1;
    __syncthreads();
    if (kc < 7) {
      const int k1 = (kc + 1)*32;
      #pragma unroll
      for (int i = 0; i < 4; ++i) aReg[i] = *(const float4*)(aSrc[i] + k1);
      bReg0 = *(const uint4*)(bSrc0 + k1);
      bReg1 = *(const uint4*)(bSrc1 + k1);
    }
    short8 aF[4], bF[4];
    #pragma unroll
    for (int mi = 0; mi < 4; ++mi)
      aF[mi] = *(const short8*)(As + (wm + mi*16 + ql)*40 + quad*8);
    #pragma unroll
    for (int ni = 0; ni < 4; ++ni)
      bF[ni] = *(const short8*)(Bs + (wn + ni*16 + ql)*40 + quad*8);
    #pragma unroll
    for (int mi = 0; mi < 4; ++mi)
      #pragma unroll
      for (int ni = 0; ni < 4; ++ni)
        acc[mi][ni] = __builtin_amdgcn_mfma_f32_16x16x32_bf16(aF[mi], bF[ni], acc[mi][ni], 0, 0, 0);
  }
  #pragma unroll
  for (int mi = 0; mi < 4; ++mi)
    #pragma unroll
    for (int r = 0; r < 4; ++r) {
      int ol = wm + mi*16 + quad*4 + r;
      int o = o0 + ol;
      float sc = ssc[ol], sh = ssh[ol];
      #pragma unroll
      for (int ni = 0; ni < 4; ++ni) {
        int n = n0 + wn + ni*16 + ql;
        long gidx = ((long)(b*Cn + o))*Nn + n;
        out[gidx] = acc[mi][ni][r]*sc + sh + x[gidx];
      }
    }
}

extern "C" void kernel_launch(void* const* d_in, const int* in_sizes, int n_in,
                              void* d_out, int out_size, void* d_ws, size_t ws_size,
                              hipStream_t stream)
{
  const float* x       = (const float*)d_in[0];
  const float* g_w     = (const float*)d_in[1];
  const float* g_b     = (const float*)d_in[2];
  const float* theta_w = (const float*)d_in[3];
  const float* theta_b = (const float*)d_in[4];
  const float* phi_w   = (const float*)d_in[5];
  const float* phi_b   = (const float*)d_in[6];
  const float* W_w     = (const float*)d_in[7];
  const float* W_b     = (const float*)d_in[8];
  const float* bn_g    = (const float*)d_in[9];
  const float* bn_b    = (const float*)d_in[10];
  const float* bn_m    = (const float*)d_in[11];
  const float* bn_v    = (const float*)d_in[12];
  float* out = (float*)d_out;

  bf16* wsb = (bf16*)d_ws;
  bf16* xT    = wsb;                  // B*N*C = 8,388,608 (dead after gemm384)
  bf16* Y     = wsb;                  // alias xT
  bf16* Q     = wsb + 8388608;        // B*N*64  = 2,097,152
  bf16* K     = wsb + 10485760;       // B*M*64  =   524,288
  bf16* Vt    = wsb + 11010048;       // B*C*M   = 2,097,152
  bf16* Wcomb = wsb + 13107200;       // 384*256 =    98,304
  float* bcomb = (float*)(wsb + 13205504);  // 384 fp32

  transpose_kernel<<<dim3(64, 4, Bn), 256, 0, stream>>>(x, xT);
  wcomb_kernel<<<dim3(384), 256, 0, stream>>>(theta_w, theta_b, phi_w, phi_b, g_w, g_b, Wcomb, bcomb);
  gemm384_kernel<<<dim3(32, 3, Bn), 256, 0, stream>>>(xT, Wcomb, bcomb, Q, K, Vt);
  attn_kernel<<<dim3(64, Bn), 512, 0, stream>>>(Q, K, Vt, Y);
  wconv_kernel<<<dim3(32, 2, Bn), 256, 0, stream>>>(Y, W_w, W_b, bn_g, bn_b, bn_m, bn_v, x, out);
}

// Round 5
// 174.702 us; speedup vs baseline: 1.3851x; 1.0457x over previous
//
#include <hip/hip_runtime.h>
#include <hip/hip_bf16.h>

typedef __hip_bfloat16 bf16;
typedef unsigned short ushort;
typedef unsigned int uint;
typedef __attribute__((ext_vector_type(8))) short short8;
typedef __attribute__((ext_vector_type(4))) float f32x4;

#define Bn 8
#define Cn 256
#define Nn 4096          // H*W
#define Mn 1024          // pooled
#define EPSf 1e-5f

__device__ __forceinline__ float b2f(const bf16 v){ return __bfloat162float(v); }
__device__ __forceinline__ ushort f2bu(float f){
  uint u = __float_as_uint(f);
  return (ushort)((u + 0x7FFFu + ((u >> 16) & 1u)) >> 16);
}

// K tiled layout (fragment-native, written by gemm384, read by attn):
//   KT(b, k16, half, lane, j) ushort idx = ((b*64 + k16)*2 + half)*512 + lane*8 + j
//   where key = k16*16 + ql, ch = half*32 + quad*8 + j, lane = quad*16 + ql.
//   One QK B-fragment = 1KB contiguous block, lane-linear (lane*16B).
// V tiled layout:
//   VT(b, mt, n16, half, lane, j) idx = (((b*16 + mt)*16 + n16)*2 + half)*512 + lane*8 + j
//   where col n = n16*16 + ql, key m = mt*64 + half*32 + quad*8 + j.
//   One PV B-fragment = 1KB contiguous block, lane-linear.

// ---------------- transpose: x[b][c][p] fp32 -> xT[b][p][c] bf16
__global__ __launch_bounds__(256) void transpose_kernel(
    const float* __restrict__ x, bf16* __restrict__ xT)
{
  __shared__ float xs[64][65];
  const int t = threadIdx.x;
  const int p0 = blockIdx.x*64, c0 = blockIdx.y*64, b = blockIdx.z;
  #pragma unroll
  for (int i = 0; i < 16; ++i) {
    int idx = t + i*256; int cl = idx >> 6, pl = idx & 63;
    xs[cl][pl] = x[((long)(b*Cn) + c0 + cl)*Nn + p0 + pl];
  }
  __syncthreads();
  ushort* xTu = (ushort*)xT;
  #pragma unroll
  for (int i = 0; i < 8; ++i) {
    int idx = t + i*256; int pl = idx >> 5, cp = idx & 31;
    uint u = (uint)f2bu(xs[cp*2][pl]) | ((uint)f2bu(xs[cp*2+1][pl]) << 16);
    *(uint*)(xTu + ((long)(b*Nn) + p0 + pl)*Cn + c0 + cp*2) = u;
  }
}

// ---------------- build combined weights Wcomb[384][256] bf16 + bcomb[384] fp32
__global__ __launch_bounds__(256) void wcomb_kernel(
    const float* __restrict__ tw, const float* __restrict__ tb,
    const float* __restrict__ pw, const float* __restrict__ pb,
    const float* __restrict__ gw, const float* __restrict__ gb,
    bf16* __restrict__ Wcomb, float* __restrict__ bcomb)
{
  const int r = blockIdx.x, c = threadIdx.x;
  float v;
  if (r < 64)        v = (c < 64)  ? tw[r*64 + c]            : 0.f;
  else if (r < 128)  v = (c >= 64) ? pw[(r-64)*192 + (c-64)] : 0.f;
  else               v = gw[(r-128)*256 + c];
  Wcomb[r*256 + c] = __float2bfloat16(v);
  if (c == 0)
    bcomb[r] = (r < 64) ? tb[r] : (r < 128) ? pb[r-64] : gb[r-128];
}

// ---------------- fused front GEMM + pooling: emits Q, K(tiled), Vt(tiled)
// grid (32 px (h-pairs), 3 o-tiles, 8 b), block 256 (4 waves, 2x2 of 64x64)
__global__ __launch_bounds__(256) void gemm384_kernel(
    const bf16* __restrict__ xT, const bf16* __restrict__ Wcomb,
    const float* __restrict__ bcomb, bf16* __restrict__ Q,
    bf16* __restrict__ K, bf16* __restrict__ Vt)
{
  __shared__ union {
    struct { ushort As[128*40]; ushort Bs[128*40]; } g;
    float Pb[2][128][33];
  } sm;
  const int t = threadIdx.x;
  const int px = blockIdx.x, o0 = blockIdx.y*128, b = blockIdx.z;
  const int p0 = px*128;
  const int lane = t & 63, w = t >> 6;
  const int ql = lane & 15, quad = lane >> 4;
  const int wm = (w & 1)*64, wn = (w >> 1)*64;
  const ushort* xTu = (const ushort*)xT;
  const ushort* Wu  = (const ushort*)Wcomb;

  // staging geometry (fixed per thread)
  const int r0 = t >> 2, cq0 = t & 3;
  const int r1 = (t + 256) >> 2, cq1 = (t + 256) & 3;
  const ushort* aSrc0 = xTu + ((long)(b*Nn) + p0 + r0)*Cn + cq0*8;
  const ushort* aSrc1 = xTu + ((long)(b*Nn) + p0 + r1)*Cn + cq1*8;
  const ushort* bSrc0 = Wu + (o0 + r0)*Cn + cq0*8;
  const ushort* bSrc1 = Wu + (o0 + r1)*Cn + cq1*8;

  f32x4 acc[4][4];
  #pragma unroll
  for (int i = 0; i < 4; ++i)
    #pragma unroll
    for (int j = 0; j < 4; ++j) acc[i][j] = (f32x4){0.f,0.f,0.f,0.f};

  // prologue: chunk-0 loads into registers
  uint4 aReg0 = *(const uint4*)(aSrc0);
  uint4 aReg1 = *(const uint4*)(aSrc1);
  uint4 bReg0 = *(const uint4*)(bSrc0);
  uint4 bReg1 = *(const uint4*)(bSrc1);

  for (int kc = 0; kc < 8; ++kc) {
    __syncthreads();
    *(uint4*)(sm.g.As + r0*40 + cq0*8) = aReg0;
    *(uint4*)(sm.g.As + r1*40 + cq1*8) = aReg1;
    *(uint4*)(sm.g.Bs + r0*40 + cq0*8) = bReg0;
    *(uint4*)(sm.g.Bs + r1*40 + cq1*8) = bReg1;
    __syncthreads();
    if (kc < 7) {
      const int k1 = (kc + 1)*32;
      aReg0 = *(const uint4*)(aSrc0 + k1);
      aReg1 = *(const uint4*)(aSrc1 + k1);
      bReg0 = *(const uint4*)(bSrc0 + k1);
      bReg1 = *(const uint4*)(bSrc1 + k1);
    }
    short8 aF[4], bF[4];
    #pragma unroll
    for (int mi = 0; mi < 4; ++mi)
      aF[mi] = *(const short8*)(sm.g.As + (wm + mi*16 + ql)*40 + quad*8);
    #pragma unroll
    for (int ni = 0; ni < 4; ++ni)
      bF[ni] = *(const short8*)(sm.g.Bs + (wn + ni*16 + ql)*40 + quad*8);
    #pragma unroll
    for (int mi = 0; mi < 4; ++mi)
      #pragma unroll
      for (int ni = 0; ni < 4; ++ni)
        acc[mi][ni] = __builtin_amdgcn_mfma_f32_16x16x32_bf16(aF[mi], bF[ni], acc[mi][ni], 0, 0, 0);
  }
  float bias[4];
  #pragma unroll
  for (int ni = 0; ni < 4; ++ni) bias[ni] = bcomb[o0 + wn + ni*16 + ql];

  if (o0 == 0 && wn == 0) {
    #pragma unroll
    for (int mi = 0; mi < 4; ++mi)
      #pragma unroll
      for (int ni = 0; ni < 4; ++ni)
        #pragma unroll
        for (int r = 0; r < 4; ++r) {
          int p = p0 + wm + mi*16 + quad*4 + r;
          Q[((long)(b*Nn) + p)*64 + ni*16 + ql] = __float2bfloat16(acc[mi][ni][r] + bias[ni]);
        }
  }
  __syncthreads();
  if (o0 != 0 || wn == 64) {
    int g = w & 1;
    #pragma unroll
    for (int mi = 0; mi < 4; ++mi)
      #pragma unroll
      for (int ni = 0; ni < 4; ++ni) {
        float a0 = acc[mi][ni][0] + bias[ni], a1 = acc[mi][ni][1] + bias[ni];
        float a2 = acc[mi][ni][2] + bias[ni], a3 = acc[mi][ni][3] + bias[ni];
        int o = wn + ni*16 + ql;
        int wp = mi*8 + quad*2;
        sm.Pb[g][o][wp]     = fmaxf(a0, a1);
        sm.Pb[g][o][wp + 1] = fmaxf(a2, a3);
      }
  }
  __syncthreads();
  if (o0 == 0) {
    // K store in fragment-tiled layout. key = px*32 + wp, ch = og*8 + j.
    int wp = t & 31, og = t >> 5;
    ushort kv[8];
    #pragma unroll
    for (int j = 0; j < 8; ++j) {
      int o = 64 + og*8 + j;
      kv[j] = f2bu(fmaxf(sm.Pb[0][o][wp], sm.Pb[1][o][wp]));
    }
    long kidx = ((long)(b*64) + px*2 + (wp>>4))*1024 + (og>>2)*512
              + ((og&3)*16 + (wp&15))*8;
    *(uint4*)((ushort*)K + kidx) = *(uint4*)kv;
  } else {
    // Vt store in fragment-tiled layout. col n, keys m = px*32 + wp0 + j'.
    int ol = t >> 1, wp0 = (t & 1)*16;
    ushort vv[16];
    #pragma unroll
    for (int j = 0; j < 16; ++j)
      vv[j] = f2bu(fmaxf(sm.Pb[0][ol][wp0 + j], sm.Pb[1][ol][wp0 + j]));
    int n = (o0 - 128) + ol;
    long vbase = (long)(b)*262144 + (px>>1)*16384 + (n>>4)*1024 + (px&1)*512;
    ushort* dst0 = (ushort*)Vt + vbase + ((wp0>>3)*16 + (n&15))*8;
    *(uint4*)dst0         = *(uint4*)(vv);
    *(uint4*)(dst0 + 128) = *(uint4*)(vv + 8);
  }
}

// ---------------- MFMA flash attention v8: zero-staging, fragment-native K/V.
// K and Vt are stored pre-tiled so each MFMA B-fragment is a 1KB contiguous,
// lane-linear block -> loaded DIRECTLY from L1/L2 into operand registers with
// full coalescing (fixes v7's 64B-scatter collapse). Only P remains in LDS
// (double-buffered) -> ONE barrier per key tile; QK(t) and PV(t-1) form one
// independent work pool between barriers. K/V fragments reuse v6's
// single-register-set prefetch (reload right after consumption, ~1 barrier
// period in flight).
//   QK: wave w -> q-row tile rt=w&3 (16 rows), key half kh=w>>2 (32 keys)
//   PV: wave w -> row half rh=(w&1)*32, col quarter cq=(w>>1)*64
__global__ __launch_bounds__(512) void attn_kernel(
    const bf16* __restrict__ Q, const bf16* __restrict__ K, const bf16* __restrict__ Vt,
    bf16* __restrict__ Y)
{
  __shared__ __align__(16) ushort Ps[2][64*68];
  __shared__ float l_sh[2][64];

  const int t = threadIdx.x;
  const int b = blockIdx.y, q0 = blockIdx.x*64;
  const int lane = t & 63, w = t >> 6;        // 8 waves
  const int ql = lane & 15, quad = lane >> 4;
  const int rt = w & 3;                        // QK row tile (16 rows)
  const int kh = w >> 2;                       // QK key half (32 keys)
  const int rh = (w & 1)*32;                   // PV local row base
  const int cq = (w >> 1)*64;                  // PV col base (64 cols)
  const ushort* Qu = (const ushort*)Q;
  const ushort* Ku = (const ushort*)K;
  const ushort* Vu = (const ushort*)Vt;

  const long qrow = (long)(b*Nn) + q0 + rt*16 + ql;
  short8 aQ0 = *(const short8*)(Qu + qrow*64 + quad*8);
  short8 aQ1 = *(const short8*)(Qu + qrow*64 + 32 + quad*8);

  // fragment base pointers (lane-linear within each 1KB block)
  const ushort* kfp = Ku + ((long)(b*64) + kh*2)*1024 + lane*8;
  // frag(mt, ct, hf) at kfp + mt*4096 + ct*1024 + hf*512
  const ushort* vfp = Vu + (long)(b)*262144 + (cq>>4)*1024 + lane*8;
  // frag(mt, ci, hf) at vfp + mt*16384 + ci*1024 + hf*512

  float lrow[4];
  #pragma unroll
  for (int r = 0; r < 4; ++r) lrow[r] = 0.f;

  f32x4 acc[2][4];
  #pragma unroll
  for (int mi = 0; mi < 2; ++mi)
    #pragma unroll
    for (int ci = 0; ci < 4; ++ci) acc[mi][ci] = (f32x4){0.f,0.f,0.f,0.f};

  short8 kf[4], vf[8];
  auto LD_K = [&](int mt){
    #pragma unroll
    for (int ct = 0; ct < 2; ++ct)
      #pragma unroll
      for (int hf = 0; hf < 2; ++hf)
        kf[ct*2+hf] = *(const short8*)(kfp + mt*4096 + ct*1024 + hf*512);
  };
  auto LD_V = [&](int mt){
    #pragma unroll
    for (int ci = 0; ci < 4; ++ci)
      #pragma unroll
      for (int hf = 0; hf < 2; ++hf)
        vf[ci*2+hf] = *(const short8*)(vfp + mt*16384 + ci*1024 + hf*512);
  };
  auto QK = [&](int sel){
    #pragma unroll
    for (int ct = 0; ct < 2; ++ct) {
      int kb = kh*32 + ct*16;
      f32x4 s = (f32x4){0.f,0.f,0.f,0.f};
      s = __builtin_amdgcn_mfma_f32_16x16x32_bf16(aQ0, kf[ct*2],   s, 0, 0, 0);
      s = __builtin_amdgcn_mfma_f32_16x16x32_bf16(aQ1, kf[ct*2+1], s, 0, 0, 0);
      #pragma unroll
      for (int r = 0; r < 4; ++r) {
        float e = __expf(s[r]);
        lrow[r] += e;
        Ps[sel][(rt*16 + quad*4 + r)*68 + kb + ql] = f2bu(e);
      }
    }
  };
  auto PV = [&](int sel){
    short8 aP0[2], aP1[2];
    #pragma unroll
    for (int mi = 0; mi < 2; ++mi) {
      aP0[mi] = *(const short8*)(&Ps[sel][(rh + mi*16 + ql)*68 + quad*8]);
      aP1[mi] = *(const short8*)(&Ps[sel][(rh + mi*16 + ql)*68 + 32 + quad*8]);
    }
    #pragma unroll
    for (int ci = 0; ci < 4; ++ci)
      #pragma unroll
      for (int mi = 0; mi < 2; ++mi) {
        acc[mi][ci] = __builtin_amdgcn_mfma_f32_16x16x32_bf16(aP0[mi], vf[ci*2],   acc[mi][ci], 0, 0, 0);
        acc[mi][ci] = __builtin_amdgcn_mfma_f32_16x16x32_bf16(aP1[mi], vf[ci*2+1], acc[mi][ci], 0, 0, 0);
      }
  };

  // prologue: tile-0 fragments, QK(0), prefetch kf(1)
  LD_K(0);
  LD_V(0);
  QK(0);
  LD_K(1);
  __syncthreads();

  for (int mt = 1; mt < 16; ++mt) {
    PV((mt-1)&1);        // consumes vf (tile mt-1)
    LD_V(mt);            // in flight until PV next iteration
    QK(mt&1);            // consumes kf (tile mt), writes Ps[mt&1]
    LD_K((mt+1)&15);     // clamped wrap on last iter (discarded reload)
    __syncthreads();     // publish Ps[mt&1]; guard Ps[(mt+1)&1] rewrite
  }
  PV(1);                 // tile 15

  // reduce l across the 16 ql lanes; each (rt,kh) wave owns a partial sum
  #pragma unroll
  for (int r = 0; r < 4; ++r)
    #pragma unroll
    for (int off = 1; off < 16; off <<= 1)
      lrow[r] += __shfl_xor(lrow[r], off, 64);
  if (ql == 0) {
    #pragma unroll
    for (int r = 0; r < 4; ++r) l_sh[kh][rt*16 + quad*4 + r] = lrow[r];
  }
  __syncthreads();
  #pragma unroll
  for (int mi = 0; mi < 2; ++mi)
    #pragma unroll
    for (int r = 0; r < 4; ++r) {
      int row = rh + mi*16 + quad*4 + r;
      float inv = 1.f / (l_sh[0][row] + l_sh[1][row]);
      #pragma unroll
      for (int ci = 0; ci < 4; ++ci)
        Y[((long)(b*Nn) + q0 + row)*256 + cq + ci*16 + ql] = __float2bfloat16(acc[mi][ci][r]*inv);
    }
}

// ---------------- wconv MFMA GEMM: out[b][o][n] = Ww @ Y^T, BN, +x
__global__ __launch_bounds__(256) void wconv_kernel(
    const bf16* __restrict__ Y, const float* __restrict__ Ww, const float* __restrict__ Wb,
    const float* __restrict__ gamma, const float* __restrict__ beta,
    const float* __restrict__ mean, const float* __restrict__ var,
    const float* __restrict__ x, float* __restrict__ out)
{
  __shared__ __align__(16) ushort As[128*40];
  __shared__ __align__(16) ushort Bs[128*40];
  __shared__ float ssc[128], ssh[128];
  const int t = threadIdx.x;
  const int n0 = blockIdx.x*128, o0 = blockIdx.y*128, b = blockIdx.z;
  const int lane = t & 63, w = t >> 6;
  const int ql = lane & 15, quad = lane >> 4;
  const int wm = (w & 1)*64, wn = (w >> 1)*64;
  const ushort* Yu = (const ushort*)Y;

  if (t < 128) {
    int o = o0 + t;
    float sc = gamma[o] * rsqrtf(var[o] + EPSf);
    ssc[t] = sc;
    ssh[t] = (Wb[o] - mean[o])*sc + beta[o];
  }

  // staging geometry (fixed per thread)
  const int ar[4] = { t >> 3, (t+256) >> 3, (t+512) >> 3, (t+768) >> 3 };
  const int ac[4] = { t & 7,  (t+256) & 7,  (t+512) & 7,  (t+768) & 7 };
  const int br0 = t >> 2, bc0 = t & 3;
  const int br1 = (t+256) >> 2, bc1 = (t+256) & 3;
  const float* aSrc[4] = {
    Ww + (o0 + ar[0])*Cn + ac[0]*4, Ww + (o0 + ar[1])*Cn + ac[1]*4,
    Ww + (o0 + ar[2])*Cn + ac[2]*4, Ww + (o0 + ar[3])*Cn + ac[3]*4 };
  const ushort* bSrc0 = Yu + ((long)(b*Nn) + n0 + br0)*Cn + bc0*8;
  const ushort* bSrc1 = Yu + ((long)(b*Nn) + n0 + br1)*Cn + bc1*8;

  f32x4 acc[4][4];
  #pragma unroll
  for (int i = 0; i < 4; ++i)
    #pragma unroll
    for (int j = 0; j < 4; ++j) acc[i][j] = (f32x4){0.f,0.f,0.f,0.f};

  // prologue: chunk-0 loads
  float4 aReg[4];
  #pragma unroll
  for (int i = 0; i < 4; ++i) aReg[i] = *(const float4*)(aSrc[i]);
  uint4 bReg0 = *(const uint4*)(bSrc0);
  uint4 bReg1 = *(const uint4*)(bSrc1);

  for (int kc = 0; kc < 8; ++kc) {
    __syncthreads();
    #pragma unroll
    for (int i = 0; i < 4; ++i) {
      uint lo = (uint)f2bu(aReg[i].x) | ((uint)f2bu(aReg[i].y) << 16);
      uint hi = (uint)f2bu(aReg[i].z) | ((uint)f2bu(aReg[i].w) << 16);
      *(uint2*)(As + ar[i]*40 + ac[i]*4) = make_uint2(lo, hi);
    }
    *(uint4*)(Bs + br0*40 + bc0*8) = bReg0;
    *(uint4*)(Bs + br1*40 + bc1*8) = bReg1;
    __syncthreads();
    if (kc < 7) {
      const int k1 = (kc + 1)*32;
      #pragma unroll
      for (int i = 0; i < 4; ++i) aReg[i] = *(const float4*)(aSrc[i] + k1);
      bReg0 = *(const uint4*)(bSrc0 + k1);
      bReg1 = *(const uint4*)(bSrc1 + k1);
    }
    short8 aF[4], bF[4];
    #pragma unroll
    for (int mi = 0; mi < 4; ++mi)
      aF[mi] = *(const short8*)(As + (wm + mi*16 + ql)*40 + quad*8);
    #pragma unroll
    for (int ni = 0; ni < 4; ++ni)
      bF[ni] = *(const short8*)(Bs + (wn + ni*16 + ql)*40 + quad*8);
    #pragma unroll
    for (int mi = 0; mi < 4; ++mi)
      #pragma unroll
      for (int ni = 0; ni < 4; ++ni)
        acc[mi][ni] = __builtin_amdgcn_mfma_f32_16x16x32_bf16(aF[mi], bF[ni], acc[mi][ni], 0, 0, 0);
  }
  #pragma unroll
  for (int mi = 0; mi < 4; ++mi)
    #pragma unroll
    for (int r = 0; r < 4; ++r) {
      int ol = wm + mi*16 + quad*4 + r;
      int o = o0 + ol;
      float sc = ssc[ol], sh = ssh[ol];
      #pragma unroll
      for (int ni = 0; ni < 4; ++ni) {
        int n = n0 + wn + ni*16 + ql;
        long gidx = ((long)(b*Cn + o))*Nn + n;
        out[gidx] = acc[mi][ni][r]*sc + sh + x[gidx];
      }
    }
}

extern "C" void kernel_launch(void* const* d_in, const int* in_sizes, int n_in,
                              void* d_out, int out_size, void* d_ws, size_t ws_size,
                              hipStream_t stream)
{
  const float* x       = (const float*)d_in[0];
  const float* g_w     = (const float*)d_in[1];
  const float* g_b     = (const float*)d_in[2];
  const float* theta_w = (const float*)d_in[3];
  const float* theta_b = (const float*)d_in[4];
  const float* phi_w   = (const float*)d_in[5];
  const float* phi_b   = (const float*)d_in[6];
  const float* W_w     = (const float*)d_in[7];
  const float* W_b     = (const float*)d_in[8];
  const float* bn_g    = (const float*)d_in[9];
  const float* bn_b    = (const float*)d_in[10];
  const float* bn_m    = (const float*)d_in[11];
  const float* bn_v    = (const float*)d_in[12];
  float* out = (float*)d_out;

  bf16* wsb = (bf16*)d_ws;
  bf16* xT    = wsb;                  // B*N*C = 8,388,608 (dead after gemm384)
  bf16* Y     = wsb;                  // alias xT
  bf16* Q     = wsb + 8388608;        // B*N*64  = 2,097,152
  bf16* K     = wsb + 10485760;       // B*M*64  =   524,288 (tiled layout)
  bf16* Vt    = wsb + 11010048;       // B*C*M   = 2,097,152 (tiled layout)
  bf16* Wcomb = wsb + 13107200;       // 384*256 =    98,304
  float* bcomb = (float*)(wsb + 13205504);  // 384 fp32

  transpose_kernel<<<dim3(64, 4, Bn), 256, 0, stream>>>(x, xT);
  wcomb_kernel<<<dim3(384), 256, 0, stream>>>(theta_w, theta_b, phi_w, phi_b, g_w, g_b, Wcomb, bcomb);
  gemm384_kernel<<<dim3(32, 3, Bn), 256, 0, stream>>>(xT, Wcomb, bcomb, Q, K, Vt);
  attn_kernel<<<dim3(64, Bn), 512, 0, stream>>>(Q, K, Vt, Y);
  wconv_kernel<<<dim3(32, 2, Bn), 256, 0, stream>>>(Y, W_w, W_b, bn_g, bn_b, bn_m, bn_v, x, out);
}

// Round 6
// 172.013 us; speedup vs baseline: 1.4068x; 1.0156x over previous
//
#include <hip/hip_runtime.h>
#include <hip/hip_bf16.h>

typedef __hip_bfloat16 bf16;
typedef unsigned short ushort;
typedef unsigned int uint;
typedef __attribute__((ext_vector_type(8))) short short8;
typedef __attribute__((ext_vector_type(4))) float f32x4;

#define Bn 8
#define Cn 256
#define Nn 4096          // H*W
#define Mn 1024          // pooled
#define EPSf 1e-5f

__device__ __forceinline__ float b2f(const bf16 v){ return __bfloat162float(v); }
__device__ __forceinline__ ushort f2bu(float f){
  uint u = __float_as_uint(f);
  return (ushort)((u + 0x7FFFu + ((u >> 16) & 1u)) >> 16);
}

// ---- fragment-tiled layouts (1KB contiguous lane-linear blocks, v8-proven) ----
// Generic MFMA B/A fragment tile for a [R][C-ch] bf16 matrix consumed as
// 16-row x 32-ch fragments: block (r16, kc) of 512 ushorts,
//   idx = (r16*8 + kc)*512 + (quad*16 + (r&15))*8 + (ch&7),  quad=(ch&31)>>3.
// xTt: (b, p16, kc)  idx = ((b*256+p16)*8+kc)*512 + lane*8   [8.4M ushorts]
// Wct: (o16, kc)     idx = ((o16*8)+kc)*512 + lane*8         [98304]
// Wwt: (o16, kc)     same, 256 rows                          [65536]
// Yt:  (b, n16, kc)  same as xTt (aliases xTt)
// K/Vt: tiled as in v8 (see gemm384 epilogue).

// ---------------- transpose: x[b][c][p] fp32 -> xTt fragment-tiled bf16
__global__ __launch_bounds__(256) void transpose_kernel(
    const float* __restrict__ x, bf16* __restrict__ xT)
{
  __shared__ float xs[64][65];
  const int t = threadIdx.x;
  const int p0 = blockIdx.x*64, c0 = blockIdx.y*64, b = blockIdx.z;
  #pragma unroll
  for (int i = 0; i < 16; ++i) {
    int idx = t + i*256; int cl = idx >> 6, pl = idx & 63;
    xs[cl][pl] = x[((long)(b*Cn) + c0 + cl)*Nn + p0 + pl];
  }
  __syncthreads();
  // write phase: per wave-iteration one (p16,kc) fragment block, fully
  // contiguous 16B/lane stores.
  ushort* xt = (ushort*)xT;
  const int ql = t & 15, quad = (t >> 4) & 3, w = t >> 6;
  #pragma unroll
  for (int i = 0; i < 2; ++i) {
    int f = w + i*4;                  // 0..7
    int p16f = f >> 1, kcf = f & 1;
    int pl = p16f*16 + ql;
    int ch0 = kcf*32 + quad*8;
    uint u[4];
    #pragma unroll
    for (int k = 0; k < 4; ++k)
      u[k] = (uint)f2bu(xs[ch0 + 2*k][pl]) | ((uint)f2bu(xs[ch0 + 2*k + 1][pl]) << 16);
    long base = ((long)b*2048 + ((p0>>4) + p16f)*8 + (c0>>5) + kcf)*512;
    *(uint4*)(xt + base + (t & 63)*8) = make_uint4(u[0], u[1], u[2], u[3]);
  }
}

// ---------------- combined weights -> tiled Wct[24 o16][8 kc] + bcomb[384]
__global__ __launch_bounds__(256) void wcomb_kernel(
    const float* __restrict__ tw, const float* __restrict__ tb,
    const float* __restrict__ pw, const float* __restrict__ pb,
    const float* __restrict__ gw, const float* __restrict__ gb,
    bf16* __restrict__ Wcomb, float* __restrict__ bcomb)
{
  const int r = blockIdx.x, c = threadIdx.x;
  float v;
  if (r < 64)        v = (c < 64)  ? tw[r*64 + c]            : 0.f;
  else if (r < 128)  v = (c >= 64) ? pw[(r-64)*192 + (c-64)] : 0.f;
  else               v = gw[(r-128)*256 + c];
  ((ushort*)Wcomb)[((r>>4)*8 + (c>>5))*512 + (((c&31)>>3)*16 + (r&15))*8 + (c&7)]
      = f2bu(v);
  if (c == 0)
    bcomb[r] = (r < 64) ? tb[r] : (r < 128) ? pb[r-64] : gb[r-128];
}

// ---------------- W_w fp32 -> tiled bf16 Wwt[16 o16][8 kc]
__global__ __launch_bounds__(256) void wwt_kernel(
    const float* __restrict__ Ww, bf16* __restrict__ Wwt)
{
  const int r = blockIdx.x, c = threadIdx.x;
  ((ushort*)Wwt)[((r>>4)*8 + (c>>5))*512 + (((c&31)>>3)*16 + (r&15))*8 + (c&7)]
      = f2bu(Ww[r*256 + c]);
}

// ---------------- fused front GEMM + pooling: zero-LDS main loop.
// A (xTt) and B (Wct) fragments loaded directly from L2 (1KB contiguous
// blocks), ping-pong 2-set register prefetch, NO barriers in main loop.
// grid (32 px, 3 o-tiles, 8 b), block 256 (4 waves, 2x2 of 64x64).
__global__ __launch_bounds__(256) void gemm384_kernel(
    const bf16* __restrict__ xTt, const bf16* __restrict__ Wct,
    const float* __restrict__ bcomb, bf16* __restrict__ Q,
    bf16* __restrict__ K, bf16* __restrict__ Vt)
{
  __shared__ float Pb[2][128][33];
  const int t = threadIdx.x;
  const int px = blockIdx.x, o0 = blockIdx.y*128, b = blockIdx.z;
  const int p0 = px*128;
  const int lane = t & 63, w = t >> 6;
  const int ql = lane & 15, quad = lane >> 4;
  const int wm = (w & 1)*64, wn = (w >> 1)*64;
  const ushort* xu = (const ushort*)xTt;
  const ushort* wu = (const ushort*)Wct;

  const ushort* aB[4]; const ushort* bB[4];
  #pragma unroll
  for (int mi = 0; mi < 4; ++mi)
    aB[mi] = xu + (((long)b*256 + px*8 + (wm>>4) + mi)*8)*512 + lane*8;
  #pragma unroll
  for (int ni = 0; ni < 4; ++ni)
    bB[ni] = wu + ((long)(((o0 + wn)>>4) + ni)*8)*512 + lane*8;

  f32x4 acc[4][4];
  #pragma unroll
  for (int i = 0; i < 4; ++i)
    #pragma unroll
    for (int j = 0; j < 4; ++j) acc[i][j] = (f32x4){0.f,0.f,0.f,0.f};

  short8 aX[4], bX[4], aY[4], bY[4];
  #pragma unroll
  for (int i = 0; i < 4; ++i) {
    aX[i] = *(const short8*)(aB[i]);
    bX[i] = *(const short8*)(bB[i]);
    aY[i] = *(const short8*)(aB[i] + 512);
    bY[i] = *(const short8*)(bB[i] + 512);
  }
  #pragma unroll
  for (int kc2 = 0; kc2 < 4; ++kc2) {
    #pragma unroll
    for (int mi = 0; mi < 4; ++mi)
      #pragma unroll
      for (int ni = 0; ni < 4; ++ni)
        acc[mi][ni] = __builtin_amdgcn_mfma_f32_16x16x32_bf16(aX[mi], bX[ni], acc[mi][ni], 0, 0, 0);
    if (kc2 < 3) {
      #pragma unroll
      for (int i = 0; i < 4; ++i) {
        aX[i] = *(const short8*)(aB[i] + (kc2*2 + 2)*512);
        bX[i] = *(const short8*)(bB[i] + (kc2*2 + 2)*512);
      }
    }
    #pragma unroll
    for (int mi = 0; mi < 4; ++mi)
      #pragma unroll
      for (int ni = 0; ni < 4; ++ni)
        acc[mi][ni] = __builtin_amdgcn_mfma_f32_16x16x32_bf16(aY[mi], bY[ni], acc[mi][ni], 0, 0, 0);
    if (kc2 < 3) {
      #pragma unroll
      for (int i = 0; i < 4; ++i) {
        aY[i] = *(const short8*)(aB[i] + (kc2*2 + 3)*512);
        bY[i] = *(const short8*)(bB[i] + (kc2*2 + 3)*512);
      }
    }
  }

  float bias[4];
  #pragma unroll
  for (int ni = 0; ni < 4; ++ni) bias[ni] = bcomb[o0 + wn + ni*16 + ql];

  if (o0 == 0 && wn == 0) {
    #pragma unroll
    for (int mi = 0; mi < 4; ++mi)
      #pragma unroll
      for (int ni = 0; ni < 4; ++ni)
        #pragma unroll
        for (int r = 0; r < 4; ++r) {
          int p = p0 + wm + mi*16 + quad*4 + r;
          Q[((long)(b*Nn) + p)*64 + ni*16 + ql] = __float2bfloat16(acc[mi][ni][r] + bias[ni]);
        }
  }
  __syncthreads();
  if (o0 != 0 || wn == 64) {
    int g = w & 1;
    #pragma unroll
    for (int mi = 0; mi < 4; ++mi)
      #pragma unroll
      for (int ni = 0; ni < 4; ++ni) {
        float a0 = acc[mi][ni][0] + bias[ni], a1 = acc[mi][ni][1] + bias[ni];
        float a2 = acc[mi][ni][2] + bias[ni], a3 = acc[mi][ni][3] + bias[ni];
        int o = wn + ni*16 + ql;
        int wp = mi*8 + quad*2;
        Pb[g][o][wp]     = fmaxf(a0, a1);
        Pb[g][o][wp + 1] = fmaxf(a2, a3);
      }
  }
  __syncthreads();
  if (o0 == 0) {
    // K store in fragment-tiled layout. key = px*32 + wp, ch = og*8 + j.
    int wp = t & 31, og = t >> 5;
    ushort kv[8];
    #pragma unroll
    for (int j = 0; j < 8; ++j) {
      int o = 64 + og*8 + j;
      kv[j] = f2bu(fmaxf(Pb[0][o][wp], Pb[1][o][wp]));
    }
    long kidx = ((long)(b*64) + px*2 + (wp>>4))*1024 + (og>>2)*512
              + ((og&3)*16 + (wp&15))*8;
    *(uint4*)((ushort*)K + kidx) = *(uint4*)kv;
  } else {
    // Vt store in fragment-tiled layout. col n, keys m = px*32 + wp0 + j'.
    int ol = t >> 1, wp0 = (t & 1)*16;
    ushort vv[16];
    #pragma unroll
    for (int j = 0; j < 16; ++j)
      vv[j] = f2bu(fmaxf(Pb[0][ol][wp0 + j], Pb[1][ol][wp0 + j]));
    int n = (o0 - 128) + ol;
    long vbase = (long)(b)*262144 + (px>>1)*16384 + (n>>4)*1024 + (px&1)*512;
    ushort* dst0 = (ushort*)Vt + vbase + ((wp0>>3)*16 + (n&15))*8;
    *(uint4*)dst0         = *(uint4*)(vv);
    *(uint4*)(dst0 + 128) = *(uint4*)(vv + 8);
  }
}

// ---------------- MFMA flash attention v8 (unchanged structure): zero-staging,
// fragment-native K/V, P double-buffered in LDS, one barrier per key tile.
// Only change: Y is stored in fragment-tiled layout (Yt) for wconv's direct
// B-fragment loads.
__global__ __launch_bounds__(512) void attn_kernel(
    const bf16* __restrict__ Q, const bf16* __restrict__ K, const bf16* __restrict__ Vt,
    bf16* __restrict__ Y)
{
  __shared__ __align__(16) ushort Ps[2][64*68];
  __shared__ float l_sh[2][64];

  const int t = threadIdx.x;
  const int b = blockIdx.y, q0 = blockIdx.x*64;
  const int lane = t & 63, w = t >> 6;        // 8 waves
  const int ql = lane & 15, quad = lane >> 4;
  const int rt = w & 3;                        // QK row tile (16 rows)
  const int kh = w >> 2;                       // QK key half (32 keys)
  const int rh = (w & 1)*32;                   // PV local row base
  const int cq = (w >> 1)*64;                  // PV col base (64 cols)
  const ushort* Qu = (const ushort*)Q;
  const ushort* Ku = (const ushort*)K;
  const ushort* Vu = (const ushort*)Vt;

  const long qrow = (long)(b*Nn) + q0 + rt*16 + ql;
  short8 aQ0 = *(const short8*)(Qu + qrow*64 + quad*8);
  short8 aQ1 = *(const short8*)(Qu + qrow*64 + 32 + quad*8);

  const ushort* kfp = Ku + ((long)(b*64) + kh*2)*1024 + lane*8;
  const ushort* vfp = Vu + (long)(b)*262144 + (cq>>4)*1024 + lane*8;

  float lrow[4];
  #pragma unroll
  for (int r = 0; r < 4; ++r) lrow[r] = 0.f;

  f32x4 acc[2][4];
  #pragma unroll
  for (int mi = 0; mi < 2; ++mi)
    #pragma unroll
    for (int ci = 0; ci < 4; ++ci) acc[mi][ci] = (f32x4){0.f,0.f,0.f,0.f};

  short8 kf[4], vf[8];
  auto LD_K = [&](int mt){
    #pragma unroll
    for (int ct = 0; ct < 2; ++ct)
      #pragma unroll
      for (int hf = 0; hf < 2; ++hf)
        kf[ct*2+hf] = *(const short8*)(kfp + mt*4096 + ct*1024 + hf*512);
  };
  auto LD_V = [&](int mt){
    #pragma unroll
    for (int ci = 0; ci < 4; ++ci)
      #pragma unroll
      for (int hf = 0; hf < 2; ++hf)
        vf[ci*2+hf] = *(const short8*)(vfp + mt*16384 + ci*1024 + hf*512);
  };
  auto QK = [&](int sel){
    #pragma unroll
    for (int ct = 0; ct < 2; ++ct) {
      int kb = kh*32 + ct*16;
      f32x4 s = (f32x4){0.f,0.f,0.f,0.f};
      s = __builtin_amdgcn_mfma_f32_16x16x32_bf16(aQ0, kf[ct*2],   s, 0, 0, 0);
      s = __builtin_amdgcn_mfma_f32_16x16x32_bf16(aQ1, kf[ct*2+1], s, 0, 0, 0);
      #pragma unroll
      for (int r = 0; r < 4; ++r) {
        float e = __expf(s[r]);
        lrow[r] += e;
        Ps[sel][(rt*16 + quad*4 + r)*68 + kb + ql] = f2bu(e);
      }
    }
  };
  auto PV = [&](int sel){
    short8 aP0[2], aP1[2];
    #pragma unroll
    for (int mi = 0; mi < 2; ++mi) {
      aP0[mi] = *(const short8*)(&Ps[sel][(rh + mi*16 + ql)*68 + quad*8]);
      aP1[mi] = *(const short8*)(&Ps[sel][(rh + mi*16 + ql)*68 + 32 + quad*8]);
    }
    #pragma unroll
    for (int ci = 0; ci < 4; ++ci)
      #pragma unroll
      for (int mi = 0; mi < 2; ++mi) {
        acc[mi][ci] = __builtin_amdgcn_mfma_f32_16x16x32_bf16(aP0[mi], vf[ci*2],   acc[mi][ci], 0, 0, 0);
        acc[mi][ci] = __builtin_amdgcn_mfma_f32_16x16x32_bf16(aP1[mi], vf[ci*2+1], acc[mi][ci], 0, 0, 0);
      }
  };

  LD_K(0);
  LD_V(0);
  QK(0);
  LD_K(1);
  __syncthreads();

  for (int mt = 1; mt < 16; ++mt) {
    PV((mt-1)&1);
    LD_V(mt);
    QK(mt&1);
    LD_K((mt+1)&15);
    __syncthreads();
  }
  PV(1);

  #pragma unroll
  for (int r = 0; r < 4; ++r)
    #pragma unroll
    for (int off = 1; off < 16; off <<= 1)
      lrow[r] += __shfl_xor(lrow[r], off, 64);
  if (ql == 0) {
    #pragma unroll
    for (int r = 0; r < 4; ++r) l_sh[kh][rt*16 + quad*4 + r] = lrow[r];
  }
  __syncthreads();
  ushort* Yu = (ushort*)Y;
  #pragma unroll
  for (int mi = 0; mi < 2; ++mi)
    #pragma unroll
    for (int r = 0; r < 4; ++r) {
      int row = rh + mi*16 + quad*4 + r;
      float inv = 1.f / (l_sh[0][row] + l_sh[1][row]);
      int n = q0 + row;
      #pragma unroll
      for (int ci = 0; ci < 4; ++ci) {
        int c = cq + ci*16 + ql;
        long idx = (((long)b*256 + (n>>4))*8 + (c>>5))*512
                 + (((c&31)>>3)*16 + (n&15))*8 + (c&7);
        Yu[idx] = f2bu(acc[mi][ci][r]*inv);
      }
    }
}

// ---------------- wconv: zero-LDS main loop, direct fragments from Wwt/Yt.
// out[b][o][n] = BN(Wwt @ Yt) + x.  grid (32, 2, 8), block 256.
__global__ __launch_bounds__(256) void wconv_kernel(
    const bf16* __restrict__ Yt, const bf16* __restrict__ Wwt, const float* __restrict__ Wb,
    const float* __restrict__ gamma, const float* __restrict__ beta,
    const float* __restrict__ mean, const float* __restrict__ var,
    const float* __restrict__ x, float* __restrict__ out)
{
  __shared__ float ssc[128], ssh[128];
  const int t = threadIdx.x;
  const int n0 = blockIdx.x*128, o0 = blockIdx.y*128, b = blockIdx.z;
  const int lane = t & 63, w = t >> 6;
  const int ql = lane & 15, quad = lane >> 4;
  const int wm = (w & 1)*64, wn = (w >> 1)*64;

  if (t < 128) {
    int o = o0 + t;
    float sc = gamma[o] * rsqrtf(var[o] + EPSf);
    ssc[t] = sc;
    ssh[t] = (Wb[o] - mean[o])*sc + beta[o];
  }

  const ushort* aB[4]; const ushort* bB[4];
  #pragma unroll
  for (int mi = 0; mi < 4; ++mi)
    aB[mi] = (const ushort*)Wwt + ((long)(((o0 + wm)>>4) + mi)*8)*512 + lane*8;
  #pragma unroll
  for (int ni = 0; ni < 4; ++ni)
    bB[ni] = (const ushort*)Yt + (((long)b*256 + ((n0 + wn)>>4) + ni)*8)*512 + lane*8;

  f32x4 acc[4][4];
  #pragma unroll
  for (int i = 0; i < 4; ++i)
    #pragma unroll
    for (int j = 0; j < 4; ++j) acc[i][j] = (f32x4){0.f,0.f,0.f,0.f};

  short8 aX[4], bX[4], aY[4], bY[4];
  #pragma unroll
  for (int i = 0; i < 4; ++i) {
    aX[i] = *(const short8*)(aB[i]);
    bX[i] = *(const short8*)(bB[i]);
    aY[i] = *(const short8*)(aB[i] + 512);
    bY[i] = *(const short8*)(bB[i] + 512);
  }
  #pragma unroll
  for (int kc2 = 0; kc2 < 4; ++kc2) {
    #pragma unroll
    for (int mi = 0; mi < 4; ++mi)
      #pragma unroll
      for (int ni = 0; ni < 4; ++ni)
        acc[mi][ni] = __builtin_amdgcn_mfma_f32_16x16x32_bf16(aX[mi], bX[ni], acc[mi][ni], 0, 0, 0);
    if (kc2 < 3) {
      #pragma unroll
      for (int i = 0; i < 4; ++i) {
        aX[i] = *(const short8*)(aB[i] + (kc2*2 + 2)*512);
        bX[i] = *(const short8*)(bB[i] + (kc2*2 + 2)*512);
      }
    }
    #pragma unroll
    for (int mi = 0; mi < 4; ++mi)
      #pragma unroll
      for (int ni = 0; ni < 4; ++ni)
        acc[mi][ni] = __builtin_amdgcn_mfma_f32_16x16x32_bf16(aY[mi], bY[ni], acc[mi][ni], 0, 0, 0);
    if (kc2 < 3) {
      #pragma unroll
      for (int i = 0; i < 4; ++i) {
        aY[i] = *(const short8*)(aB[i] + (kc2*2 + 3)*512);
        bY[i] = *(const short8*)(bB[i] + (kc2*2 + 3)*512);
      }
    }
  }
  __syncthreads();   // ssc/ssh visible to all
  #pragma unroll
  for (int mi = 0; mi < 4; ++mi)
    #pragma unroll
    for (int r = 0; r < 4; ++r) {
      int ol = wm + mi*16 + quad*4 + r;
      int o = o0 + ol;
      float sc = ssc[ol], sh = ssh[ol];
      #pragma unroll
      for (int ni = 0; ni < 4; ++ni) {
        int n = n0 + wn + ni*16 + ql;
        long gidx = ((long)(b*Cn + o))*Nn + n;
        out[gidx] = acc[mi][ni][r]*sc + sh + x[gidx];
      }
    }
}

extern "C" void kernel_launch(void* const* d_in, const int* in_sizes, int n_in,
                              void* d_out, int out_size, void* d_ws, size_t ws_size,
                              hipStream_t stream)
{
  const float* x       = (const float*)d_in[0];
  const float* g_w     = (const float*)d_in[1];
  const float* g_b     = (const float*)d_in[2];
  const float* theta_w = (const float*)d_in[3];
  const float* theta_b = (const float*)d_in[4];
  const float* phi_w   = (const float*)d_in[5];
  const float* phi_b   = (const float*)d_in[6];
  const float* W_w     = (const float*)d_in[7];
  const float* W_b     = (const float*)d_in[8];
  const float* bn_g    = (const float*)d_in[9];
  const float* bn_b    = (const float*)d_in[10];
  const float* bn_m    = (const float*)d_in[11];
  const float* bn_v    = (const float*)d_in[12];
  float* out = (float*)d_out;

  bf16* wsb = (bf16*)d_ws;
  bf16* xTt   = wsb;                  // B*N*C = 8,388,608 (dead after gemm384)
  bf16* Yt    = wsb;                  // alias xTt (tiled layout)
  bf16* Q     = wsb + 8388608;        // B*N*64  = 2,097,152
  bf16* K     = wsb + 10485760;       // B*M*64  =   524,288 (tiled)
  bf16* Vt    = wsb + 11010048;       // B*C*M   = 2,097,152 (tiled)
  bf16* Wct   = wsb + 13107200;       // 384*256 =    98,304 (tiled)
  float* bcomb = (float*)(wsb + 13205504);  // 384 fp32 (= 768 ushorts)
  bf16* Wwt   = wsb + 13206272;       // 256*256 =    65,536 (tiled)

  transpose_kernel<<<dim3(64, 4, Bn), 256, 0, stream>>>(x, xTt);
  wcomb_kernel<<<dim3(384), 256, 0, stream>>>(theta_w, theta_b, phi_w, phi_b, g_w, g_b, Wct, bcomb);
  wwt_kernel<<<dim3(256), 256, 0, stream>>>(W_w, Wwt);
  gemm384_kernel<<<dim3(32, 3, Bn), 256, 0, stream>>>(xTt, Wct, bcomb, Q, K, Vt);
  attn_kernel<<<dim3(64, Bn), 512, 0, stream>>>(Q, K, Vt, Yt);
  wconv_kernel<<<dim3(32, 2, Bn), 256, 0, stream>>>(Yt, Wwt, W_b, bn_g, bn_b, bn_m, bn_v, x, out);
}